// Round 2
// baseline (166.442 us; speedup 1.0000x reference)
//
#include <hip/hip_runtime.h>
#include <hip/hip_bf16.h>

#define SS 2048
#define DD 128
#define BB 16

typedef short bf16x8 __attribute__((ext_vector_type(8)));
typedef float f32x4 __attribute__((ext_vector_type(4)));
typedef unsigned short ushort_t;

__device__ __forceinline__ unsigned short f2bf(float f) {
  union { float f; unsigned u; } v; v.f = f;
  unsigned r = v.u + 0x7fffu + ((v.u >> 16) & 1u);  // RNE
  return (unsigned short)(r >> 16);
}
__device__ __forceinline__ float fexp2(float x) { return __builtin_amdgcn_exp2f(x); }

// ---------------------------------------------------------------------------
// prep: blocks 0..2047 convert x fp32->bf16 (xb); blocks 2048..2111 build
// wt_g = [Wq^T*log2e/sqrt(U) ; Wk^T] as bf16 [256][128].
// ---------------------------------------------------------------------------
__global__ __launch_bounds__(256) void prep(
    const float* __restrict__ x, const float* __restrict__ Wq,
    const float* __restrict__ Wk, ushort_t* __restrict__ xb,
    ushort_t* __restrict__ wt_g) {
  const int tid = threadIdx.x, blk = blockIdx.x;
  if (blk < 2048) {
    size_t i = ((size_t)blk * 256 + tid) * 8;
    const float4 a = *(const float4*)(x + i);
    const float4 c = *(const float4*)(x + i + 4);
    union { ushort_t s[8]; uint4 v; } u;
    u.s[0] = f2bf(a.x); u.s[1] = f2bf(a.y); u.s[2] = f2bf(a.z); u.s[3] = f2bf(a.w);
    u.s[4] = f2bf(c.x); u.s[5] = f2bf(c.y); u.s[6] = f2bf(c.z); u.s[7] = f2bf(c.w);
    *(uint4*)(xb + i) = u.v;
  } else {
    int idx = (blk - 2048) * 256 + tid;  // 0..16383
    int uu = idx >> 7, d = idx & 127;
    wt_g[uu * 128 + d] = f2bf(Wq[d * 128 + uu] * 0.1275174346f);  // log2e/sqrt(128)
    wt_g[(uu + 128) * 128 + d] = f2bf(Wk[d * 128 + uu]);
  }
}

// ---------------------------------------------------------------------------
// qk_gemm: [qb|kb] = xb @ wt_g^T.  grid 512 (64 M-rows per block), block 256.
// Wave w owns rows [w*16, +16). A/B frags loaded DIRECT from global (no LDS
// in main loop); C repacked via LDS scratch for coalesced uint4 stores.
// ---------------------------------------------------------------------------
#define SCT 264  // 256 + 8 pad
__global__ __launch_bounds__(256) void qk_gemm(
    const ushort_t* __restrict__ xb, const ushort_t* __restrict__ wt_g,
    ushort_t* __restrict__ qb, ushort_t* __restrict__ kb) {
  __shared__ ushort_t sc[64 * SCT];
  const int tid = threadIdx.x, wave = tid >> 6, lane = tid & 63;
  const int lq = lane & 15, quad = lane >> 4;
  const int m0 = blockIdx.x * 64;

  bf16x8 af[4];
  const ushort_t* xrow = xb + (size_t)(m0 + wave * 16 + lq) * DD + quad * 8;
#pragma unroll
  for (int ks = 0; ks < 4; ++ks) af[ks] = *(const bf16x8*)(xrow + ks * 32);

#pragma unroll
  for (int nt = 0; nt < 8; ++nt) {  // pair q-col-tile nt with k-col-tile nt+8
    f32x4 aq = (f32x4){0.f, 0.f, 0.f, 0.f};
    f32x4 ak = (f32x4){0.f, 0.f, 0.f, 0.f};
#pragma unroll
    for (int ks = 0; ks < 4; ++ks) {
      bf16x8 bq = *(const bf16x8*)(wt_g + (nt * 16 + lq) * 128 + ks * 32 + quad * 8);
      bf16x8 bk = *(const bf16x8*)(wt_g + ((nt + 8) * 16 + lq) * 128 + ks * 32 + quad * 8);
      aq = __builtin_amdgcn_mfma_f32_16x16x32_bf16(af[ks], bq, aq, 0, 0, 0);
      ak = __builtin_amdgcn_mfma_f32_16x16x32_bf16(af[ks], bk, ak, 0, 0, 0);
    }
#pragma unroll
    for (int r = 0; r < 4; ++r) {
      int row = wave * 16 + quad * 4 + r;
      sc[row * SCT + nt * 16 + lq] = f2bf(aq[r]);
      sc[row * SCT + 128 + nt * 16 + lq] = f2bf(ak[r]);
    }
  }
  __syncthreads();
#pragma unroll
  for (int i = 0; i < 4; ++i) {  // 64 rows x 128 cols each, uint4 chunks
    int idx = i * 256 + tid;
    int row = idx >> 4, col = (idx & 15) * 8;
    *(uint4*)(qb + (size_t)(m0 + row) * DD + col) = *(const uint4*)(&sc[row * SCT + col]);
    *(uint4*)(kb + (size_t)(m0 + row) * DD + col) = *(const uint4*)(&sc[row * SCT + 128 + col]);
  }
}

// ---------------------------------------------------------------------------
// attn_ce: barrier-free K-loop, direct-global B frags, ping-pong prefetch.
// grid 512 = 16 b x 32 i-blocks(64 rows); block 256; wave w owns j-cols
// [w*32,+32) of each 128-col tile.
// ---------------------------------------------------------------------------
__global__ __launch_bounds__(256, 2) void attn_ce(
    const ushort_t* __restrict__ qb, const ushort_t* __restrict__ kb,
    const float* __restrict__ t, const float* __restrict__ theta,
    const float* __restrict__ mu, float* __restrict__ w) {
  const int b = blockIdx.x >> 5;
  const int i0 = (blockIdx.x & 31) * 64;
  const int tid = threadIdx.x, wave = tid >> 6, lane = tid & 63;
  const int lq = lane & 15, quad = lane >> 4;

  __shared__ float rs_lds[4][64];
  __shared__ float c_lds[64];

  // A fragments: 64 q-rows x K=128, register-resident for both passes
  bf16x8 af[4][4];
  const ushort_t* qbase = qb + (size_t)(b * SS + i0 + lq) * DD + quad * 8;
#pragma unroll
  for (int mt = 0; mt < 4; ++mt)
#pragma unroll
    for (int ks = 0; ks < 4; ++ks)
      af[mt][ks] = *(const bf16x8*)(qbase + mt * 16 * DD + ks * 32);

  const ushort_t* kwave = kb + (size_t)(b * SS + wave * 32 + lq) * DD + quad * 8;

  bf16x8 cur[2][4], nxt[2][4];
  auto load_tile = [&](bf16x8 (&f)[2][4], int jt) {
    const ushort_t* base = kwave + (size_t)jt * 128 * DD;
#pragma unroll
    for (int nt = 0; nt < 2; ++nt)
#pragma unroll
      for (int ks = 0; ks < 4; ++ks)
        f[nt][ks] = *(const bf16x8*)(base + nt * 16 * DD + ks * 32);
  };

  float rowsum[4][4];
#pragma unroll
  for (int mt = 0; mt < 4; ++mt)
#pragma unroll
    for (int r = 0; r < 4; ++r) rowsum[mt][r] = 0.f;

  auto compute_p1 = [&](bf16x8 (&f)[2][4]) {
#pragma unroll
    for (int nt = 0; nt < 2; ++nt) {
      f32x4 acc[4];
#pragma unroll
      for (int mt = 0; mt < 4; ++mt) acc[mt] = (f32x4){0.f, 0.f, 0.f, 0.f};
#pragma unroll
      for (int ks = 0; ks < 4; ++ks)
#pragma unroll
        for (int mt = 0; mt < 4; ++mt)
          acc[mt] = __builtin_amdgcn_mfma_f32_16x16x32_bf16(af[mt][ks], f[nt][ks], acc[mt], 0, 0, 0);
#pragma unroll
      for (int mt = 0; mt < 4; ++mt)
#pragma unroll
        for (int r = 0; r < 4; ++r) rowsum[mt][r] += fexp2(acc[mt][r]);
    }
  };

  // ---- PASS 1: row sums (barrier-free) ----
  load_tile(cur, 0);
  for (int jt = 0; jt < 16; jt += 2) {
    load_tile(nxt, jt + 1);
    compute_p1(cur);
    if (jt + 2 < 16) load_tile(cur, jt + 2);
    compute_p1(nxt);
  }

  // reduce rowsums over the 16 col-lanes
#pragma unroll
  for (int d2 = 1; d2 <= 8; d2 <<= 1)
#pragma unroll
    for (int mt = 0; mt < 4; ++mt)
#pragma unroll
      for (int r = 0; r < 4; ++r)
        rowsum[mt][r] += __shfl_xor(rowsum[mt][r], d2, 64);
  if (lq == 0) {
#pragma unroll
    for (int mt = 0; mt < 4; ++mt)
#pragma unroll
      for (int r = 0; r < 4; ++r)
        rs_lds[wave][mt * 16 + quad * 4 + r] = rowsum[mt][r];
  }
  __syncthreads();
  if (tid < 64) {
    float l = rs_lds[0][tid] + rs_lds[1][tid] + rs_lds[2][tid] + rs_lds[3][tid];
    int gi = i0 + tid;
    float z = theta[gi] - mu[gi] * t[b * SS + gi];
    float tf = 1.f / (1.f + fexp2(-z * 1.44269504f));
    c_lds[tid] = tf / l;
  }
  __syncthreads();
  float creg[4][4];
#pragma unroll
  for (int mt = 0; mt < 4; ++mt)
#pragma unroll
    for (int r = 0; r < 4; ++r) creg[mt][r] = c_lds[mt * 16 + quad * 4 + r];

  auto compute_p2 = [&](bf16x8 (&f)[2][4], int jt) {
#pragma unroll
    for (int nt = 0; nt < 2; ++nt) {
      f32x4 acc[4];
#pragma unroll
      for (int mt = 0; mt < 4; ++mt) acc[mt] = (f32x4){0.f, 0.f, 0.f, 0.f};
#pragma unroll
      for (int ks = 0; ks < 4; ++ks)
#pragma unroll
        for (int mt = 0; mt < 4; ++mt)
          acc[mt] = __builtin_amdgcn_mfma_f32_16x16x32_bf16(af[mt][ks], f[nt][ks], acc[mt], 0, 0, 0);
      float cs = 0.f;
#pragma unroll
      for (int mt = 0; mt < 4; ++mt)
#pragma unroll
        for (int r = 0; r < 4; ++r) cs = fmaf(creg[mt][r], fexp2(acc[mt][r]), cs);
      cs += __shfl_xor(cs, 16, 64);
      cs += __shfl_xor(cs, 32, 64);
      if (lane < 16)
        atomicAdd(&w[b * SS + jt * 128 + wave * 32 + nt * 16 + lane], cs);
    }
  };

  // ---- PASS 2: column sums -> w (barrier-free) ----
  load_tile(cur, 0);
  for (int jt = 0; jt < 16; jt += 2) {
    load_tile(nxt, jt + 1);
    compute_p2(cur, jt);
    if (jt + 2 < 16) load_tile(cur, jt + 2);
    compute_p2(nxt, jt + 1);
  }
}

// ---------------------------------------------------------------------------
// finalize: v[b,d] = sum_j w[b,j] * x[b,j,d].  grid 512 (64 j per block).
// ---------------------------------------------------------------------------
__global__ __launch_bounds__(256) void finalize(
    const float* __restrict__ x, const float* __restrict__ w,
    float* __restrict__ out) {
  const int b = blockIdx.x >> 5;
  const int j0 = (blockIdx.x & 31) * 64;
  const int tid = threadIdx.x;
  const int d = tid & 127, jo = tid >> 7;
  float acc = 0.f;
  for (int jj = 0; jj < 32; ++jj) {
    int j = j0 + jj * 2 + jo;
    acc = fmaf(w[b * SS + j], x[((size_t)b * SS + j) * DD + d], acc);
  }
  __shared__ float red[256];
  red[tid] = acc;
  __syncthreads();
  if (tid < 128) atomicAdd(&out[b * DD + tid], red[tid] + red[tid + 128]);
}

extern "C" void kernel_launch(void* const* d_in, const int* in_sizes, int n_in,
                              void* d_out, int out_size, void* d_ws, size_t ws_size,
                              hipStream_t stream) {
  const float* x = (const float*)d_in[0];
  const float* t = (const float*)d_in[1];
  const float* Wq = (const float*)d_in[2];
  const float* Wk = (const float*)d_in[3];
  const float* theta = (const float*)d_in[4];
  const float* mu = (const float*)d_in[5];
  float* out = (float*)d_out;

  ushort_t* qb = (ushort_t*)d_ws;                       // 8.4 MB
  ushort_t* kb = qb + (size_t)BB * SS * DD;             // 8.4 MB
  ushort_t* xb = kb + (size_t)BB * SS * DD;             // 8.4 MB
  ushort_t* wt_g = xb + (size_t)BB * SS * DD;           // 64 KB
  float* w = (float*)(wt_g + 256 * 128);                // 131 KB

  hipMemsetAsync(w, 0, (size_t)BB * SS * sizeof(float), stream);
  hipMemsetAsync(d_out, 0, (size_t)BB * DD * sizeof(float), stream);

  prep<<<dim3(2112), dim3(256), 0, stream>>>(x, Wq, Wk, xb, wt_g);
  qk_gemm<<<dim3(512), dim3(256), 0, stream>>>(xb, wt_g, qb, kb);
  attn_ce<<<dim3(512), dim3(256), 0, stream>>>(qb, kb, t, theta, mu, w);
  finalize<<<dim3(512), dim3(256), 0, stream>>>(x, w, out);
}